// Round 10
// baseline (290.845 us; speedup 1.0000x reference)
//
#include <hip/hip_runtime.h>
#include <math.h>

#define B  2
#define L  4096
#define D  512
#define H  8
#define DH 64
#define BH (B * H)
#define K3 1536          // tripled-K for the bf16 split GEMM (Q,K)
#define XPW 1024         // Xp width: [hi | lo]

typedef short s16x8 __attribute__((ext_vector_type(8)));
typedef float f32x4 __attribute__((ext_vector_type(4)));

#define AS1 __attribute__((address_space(1)))
#define AS3 __attribute__((address_space(3)))

__device__ __forceinline__ void lds_load16(const void* g, void* l) {
    __builtin_amdgcn_global_load_lds((const AS1 unsigned int*)g,
                                     (AS3 unsigned int*)l, 16, 0, 0);
}

__device__ __forceinline__ unsigned short f2bf(float x) {
    union { float f; unsigned u; } v; v.f = x;
    unsigned u = v.u;
    return (unsigned short)((u + 0x7fff + ((u >> 16) & 1)) >> 16);
}
__device__ __forceinline__ float bf2f(unsigned short h) {
    union { float f; unsigned u; } v; v.u = ((unsigned)h) << 16;
    return v.f;
}

// ---------------------------------------------------------------------------
// Prep 1: split X (fp32 8192x512) -> Xp (bf16 8192x1024): [hi | lo]
// V (e==2) needs only hi.
// ---------------------------------------------------------------------------
__global__ __launch_bounds__(256)
void split_x(const float* __restrict__ q, const float* __restrict__ k,
             const float* __restrict__ v, unsigned short* __restrict__ Xp)
{
    const size_t g = (size_t)blockIdx.x * 256 + threadIdx.x;
    const size_t per = (size_t)8192 * 128;
    const int e = (int)(g / per);
    const size_t rem = g - (size_t)e * per;
    const int m  = (int)(rem >> 7);
    const int kq = (int)(rem & 127) << 2;

    const float* X = (e == 0) ? q : (e == 1) ? k : v;
    const float4 x = *(const float4*)(X + (size_t)m * 512 + kq);

    unsigned short h0 = f2bf(x.x), h1 = f2bf(x.y), h2 = f2bf(x.z), h3 = f2bf(x.w);

    unsigned short* dst = Xp + (size_t)e * 8192 * XPW + (size_t)m * XPW + kq;
    *(ushort4*)(dst) = make_ushort4(h0, h1, h2, h3);
    if (e != 2) {
        unsigned short l0 = f2bf(x.x - bf2f(h0)), l1 = f2bf(x.y - bf2f(h1));
        unsigned short l2 = f2bf(x.z - bf2f(h2)), l3 = f2bf(x.w - bf2f(h3));
        *(ushort4*)(dst + 512) = make_ushort4(l0, l1, l2, l3);
    }
}

// ---------------------------------------------------------------------------
// Prep 2: W -> WpT (bf16 512x1536, [n][k']): [hi | lo | hi]
// ---------------------------------------------------------------------------
__global__ __launch_bounds__(256)
void split_w(const float* __restrict__ wq, const float* __restrict__ wk,
             const float* __restrict__ wv, unsigned short* __restrict__ WpT)
{
    __shared__ float t[64][65];
    const int e  = blockIdx.z;
    const int k0 = blockIdx.x * 64;
    const int n0 = blockIdx.y * 64;
    const float* W = (e == 0) ? wq : (e == 1) ? wk : wv;
    const int tid = threadIdx.x;

    for (int idx = tid; idx < 64 * 16; idx += 256) {
        const int i = idx >> 4, j4 = (idx & 15) << 2;
        *(float4*)&t[i][j4] = *(const float4*)(W + (size_t)(k0 + i) * 512 + n0 + j4);
    }
    __syncthreads();

    const int n_loc = tid >> 2;
    const int kq    = (tid & 3) << 4;
    unsigned short h[16], l[16];
    #pragma unroll
    for (int tt = 0; tt < 16; tt++) {
        const float x = t[kq + tt][n_loc];
        h[tt] = f2bf(x);
        l[tt] = f2bf(x - bf2f(h[tt]));
    }
    unsigned short* base = WpT + (size_t)e * 512 * K3 + (size_t)(n0 + n_loc) * K3 + k0 + kq;
    #pragma unroll
    for (int g4 = 0; g4 < 4; g4++) {
        ushort4 hv = make_ushort4(h[g4*4], h[g4*4+1], h[g4*4+2], h[g4*4+3]);
        ushort4 lv = make_ushort4(l[g4*4], l[g4*4+1], l[g4*4+2], l[g4*4+3]);
        *(ushort4*)(base + g4*4)        = hv;
        *(ushort4*)(base + 512 + g4*4)  = lv;
        *(ushort4*)(base + 1024 + g4*4) = hv;
    }
}

// ---------------------------------------------------------------------------
// Kernel 1: bf16-split MFMA GEMM. 128x128 tile, BK=32, 4 waves.
// ---------------------------------------------------------------------------
__global__ __launch_bounds__(256)
void gemm_mfma(const unsigned short* __restrict__ Xp,
               const unsigned short* __restrict__ WpT,
               const float* __restrict__ bq, const float* __restrict__ bk,
               const float* __restrict__ bv,
               float* __restrict__ Qo, float* __restrict__ Ko,
               float* __restrict__ Vo)
{
    __shared__ __align__(16) unsigned short smA[4096];
    __shared__ __align__(16) unsigned short smB[4096];

    const int e = blockIdx.z;
    const float* bias = (e == 0) ? bq : (e == 1) ? bk : bv;
    float* C          = (e == 0) ? Qo : (e == 1) ? Ko : Vo;
    const unsigned short* Ag = Xp  + (size_t)e * 8192 * XPW;
    const unsigned short* Bg = WpT + (size_t)e * 512 * K3;
    const int kEnd = (e == 2) ? 512 : K3;

    const int tid  = threadIdx.x;
    const int lane = tid & 63;
    const int wid  = tid >> 6;
    const int wm   = wid & 1;
    const int wn   = wid >> 1;
    const int m0   = blockIdx.x * 128;
    const int n0g  = blockIdx.y * 128;

    const int r1 = tid >> 2;
    const int c8 = (((tid & 3) ^ ((r1 >> 1) & 3)) << 3);
    const unsigned short* agp = Ag + (size_t)(m0 + r1) * XPW + c8;
    const unsigned short* bgp = Bg + (size_t)(n0g + r1) * K3 + c8;
    unsigned short* lA1 = smA + (size_t)(tid & ~63) * 8;
    unsigned short* lA2 = lA1 + 2048;
    unsigned short* lB1 = smB + (size_t)(tid & ~63) * 8;
    unsigned short* lB2 = lB1 + 2048;

    const int r    = lane & 15;
    const int quad = lane >> 4;
    const int swz  = ((quad ^ ((lane >> 1) & 3)) << 4);
    const char* pA = (const char*)smA + (wm * 64 + r) * 64 + swz;
    const char* pB = (const char*)smB + (wn * 64 + r) * 64 + swz;

    f32x4 acc[4][4];
    #pragma unroll
    for (int i = 0; i < 4; i++)
        #pragma unroll
        for (int j = 0; j < 4; j++)
            acc[i][j] = (f32x4){0.f, 0.f, 0.f, 0.f};

    for (int k0 = 0; k0 < kEnd; k0 += 32) {
        const int kA = (k0 < 512) ? k0 : k0 - 512;
        lds_load16(agp + kA, lA1);
        lds_load16(agp + (size_t)64 * XPW + kA, lA2);
        lds_load16(bgp + k0, lB1);
        lds_load16(bgp + (size_t)64 * K3 + k0, lB2);
        __syncthreads();

        s16x8 af[4], bf[4];
        #pragma unroll
        for (int mt = 0; mt < 4; mt++) af[mt] = *(const s16x8*)(pA + mt * 1024);
        #pragma unroll
        for (int nt = 0; nt < 4; nt++) bf[nt] = *(const s16x8*)(pB + nt * 1024);
        #pragma unroll
        for (int mt = 0; mt < 4; mt++)
            #pragma unroll
            for (int nt = 0; nt < 4; nt++)
                acc[mt][nt] = __builtin_amdgcn_mfma_f32_16x16x32_bf16(
                    af[mt], bf[nt], acc[mt][nt], 0, 0, 0);
        __syncthreads();
    }

    #pragma unroll
    for (int nt = 0; nt < 4; nt++) {
        const int col = n0g + wn * 64 + nt * 16 + r;
        const float bb = bias[col];
        #pragma unroll
        for (int mt = 0; mt < 4; mt++) {
            const int row0 = m0 + wm * 64 + mt * 16 + quad * 4;
            #pragma unroll
            for (int i = 0; i < 4; i++)
                C[(size_t)(row0 + i) * 512 + col] = acc[mt][nt][i] + bb;
        }
    }
}

// ---------------------------------------------------------------------------
// Kernel 2: m[b,h,l] = max_s(q.k_s) - sum_s(q.k_s)/L. Wave per query.
// ---------------------------------------------------------------------------
__global__ __launch_bounds__(256)
void sample_m(const float* __restrict__ Q, const float* __restrict__ K,
              const int* __restrict__ idx, float* __restrict__ m_out, int S)
{
    __shared__ float qs[4][DH];

    const int lane = threadIdx.x & 63;
    const int wib  = threadIdx.x >> 6;
    const int wid  = blockIdx.x * 4 + wib;
    const int l = wid & (L - 1);
    const int h = (wid >> 12) & (H - 1);
    const int b = wid >> 15;

    qs[wib][lane] = Q[((size_t)b * L + l) * D + h * DH + lane];
    __syncthreads();

    const int r4 = lane >> 2;
    const int c4 = lane & 3;

    float4 qf[4];
    {
        const float4* qv = (const float4*)qs[wib];
        #pragma unroll
        for (int i = 0; i < 4; i++) qf[i] = qv[c4 + 4 * i];
    }

    const float* Kb = K + (size_t)b * L * D + h * DH;
    const int* is = idx + (size_t)l * S;

    float vmax = -INFINITY, vsum = 0.f;
    const int passes = (S + 15) >> 4;
    for (int p = 0; p < passes; p++) {
        const int sp = p * 16 + r4;
        const bool ok = sp < S;
        const int j = ok ? is[sp] : 0;
        const float4* Krow = (const float4*)(Kb + (size_t)j * D);
        float dot = 0.f;
        #pragma unroll
        for (int i = 0; i < 4; i++) {
            const float4 kv = Krow[c4 + 4 * i];
            const float4 qq = qf[i];
            dot += qq.x * kv.x + qq.y * kv.y + qq.z * kv.z + qq.w * kv.w;
        }
        dot += __shfl_xor(dot, 1, 64);
        dot += __shfl_xor(dot, 2, 64);
        if (ok) {
            vmax = fmaxf(vmax, dot);
            if (c4 == 0) vsum += dot;
        }
    }
    #pragma unroll
    for (int off = 32; off; off >>= 1) {
        vmax = fmaxf(vmax, __shfl_xor(vmax, off, 64));
        vsum += __shfl_xor(vsum, off, 64);
    }
    if (lane == 0) m_out[wid] = vmax - vsum * (1.0f / (float)L);
}

// ---------------------------------------------------------------------------
// Kernel 3: exact top-NT via 4-level byte radix-select. One block per (b,h).
// Also zeroes sums[] and writes the selected-row flag array.
// ---------------------------------------------------------------------------
__global__ __launch_bounds__(256)
void topk_kernel(const float* __restrict__ m_in, int* __restrict__ m_top,
                 float* __restrict__ sums, int* __restrict__ flags, int NT)
{
    __shared__ unsigned hist[256];
    __shared__ unsigned sfx[257];
    __shared__ int sh_b, sh_rem;
    __shared__ int cnt_gt, cnt_eq;
    __shared__ int eqlist[128];

    const float* m = m_in + (size_t)blockIdx.x * L;
    const int tid = threadIdx.x;
    int* out = m_top + blockIdx.x * NT;
    int* fl  = flags + (size_t)blockIdx.x * L;

    if (tid < NT) sums[blockIdx.x * NT + tid] = 0.f;
    for (int i = tid; i < L; i += 256) fl[i] = 0;

    unsigned uv[16];
    #pragma unroll
    for (int k = 0; k < 16; k++) {
        const float f = m[tid + k * 256];
        const unsigned x = __float_as_uint(f);
        uv[k] = (x & 0x80000000u) ? ~x : (x | 0x80000000u);
    }

    unsigned prefix = 0;
    int rem = NT;

    for (int level = 0; level < 4; level++) {
        const int shift = 24 - level * 8;
        hist[tid] = 0;
        if (tid == 0) { cnt_gt = 0; cnt_eq = 0; }
        __syncthreads();
        #pragma unroll
        for (int k = 0; k < 16; k++) {
            const bool part = (level == 0) || ((uv[k] >> (shift + 8)) == prefix);
            if (part) atomicAdd(&hist[(uv[k] >> shift) & 255], 1u);
        }
        __syncthreads();
        if (tid < 64) {
            const unsigned s0 = hist[4*tid+0], s1 = hist[4*tid+1];
            const unsigned s2 = hist[4*tid+2], s3 = hist[4*tid+3];
            const unsigned loc = s0 + s1 + s2 + s3;
            unsigned suf = loc;
            #pragma unroll
            for (int off = 1; off < 64; off <<= 1) {
                const unsigned t = __shfl_down(suf, off, 64);
                if (tid + off < 64) suf += t;
            }
            const unsigned tail = suf - loc;
            sfx[4*tid+3] = tail + s3;
            sfx[4*tid+2] = tail + s3 + s2;
            sfx[4*tid+1] = tail + s3 + s2 + s1;
            sfx[4*tid+0] = suf;
            if (tid == 0) sfx[256] = 0;
        }
        __syncthreads();
        if (sfx[tid + 1] < (unsigned)rem && (unsigned)rem <= sfx[tid]) {
            sh_b   = tid;
            sh_rem = rem - (int)sfx[tid + 1];
        }
        __syncthreads();
        prefix = (prefix << 8) | (unsigned)sh_b;
        rem    = sh_rem;
        __syncthreads();
    }

    const unsigned T = prefix;
    const int n_gt = NT - rem;

    #pragma unroll
    for (int k = 0; k < 16; k++) {
        if (uv[k] > T) {
            const int pos = atomicAdd(&cnt_gt, 1);
            out[pos] = tid + k * 256;
        } else if (uv[k] == T) {
            const int pos = atomicAdd(&cnt_eq, 1);
            if (pos < 128) eqlist[pos] = tid + k * 256;
        }
    }
    __syncthreads();
    if (tid == 0) {
        int n = cnt_eq < 128 ? cnt_eq : 128;
        for (int r = 0; r < rem; r++) {
            int best = 0x7fffffff, bi = 0;
            for (int i = 0; i < n; i++)
                if (eqlist[i] < best) { best = eqlist[i]; bi = i; }
            out[n_gt + r] = best;
            eqlist[bi] = 0x7fffffff;
        }
    }
    __syncthreads();
    if (tid < NT) fl[out[tid]] = 1;
}

// ---------------------------------------------------------------------------
// Kernels 4+5: cumsum(V), chunked scan. cumsum_write zeroes selected rows
// (flag-gated) so the fused attention can accumulate into them.
// ---------------------------------------------------------------------------
#define CH 64
__global__ __launch_bounds__(256)
void chunk_sums(const float* __restrict__ V, float* __restrict__ partial)
{
    const int c  = (blockIdx.x & 15) * 4 + (threadIdx.x >> 6);
    const int h  = (blockIdx.x >> 4) & (H - 1);
    const int b  = blockIdx.x >> 7;
    const int d  = threadIdx.x & 63;
    const float* base = V + (size_t)b * L * D + h * DH + d + (size_t)(c * CH) * D;

    float vals[CH];
    #pragma unroll
    for (int i = 0; i < CH; i++) vals[i] = base[(size_t)i * D];

    float s0 = 0.f, s1 = 0.f, s2 = 0.f, s3 = 0.f;
    #pragma unroll
    for (int i = 0; i < CH; i += 4) {
        s0 += vals[i]; s1 += vals[i+1]; s2 += vals[i+2]; s3 += vals[i+3];
    }
    partial[((size_t)((b * H + h) * 64 + c)) * DH + d] = (s0 + s1) + (s2 + s3);
}

__global__ __launch_bounds__(256)
void cumsum_write(const float* __restrict__ V, const float* __restrict__ partial,
                  const int* __restrict__ flags, float* __restrict__ out)
{
    const int c  = (blockIdx.x & 15) * 4 + (threadIdx.x >> 6);
    const int h  = (blockIdx.x >> 4) & (H - 1);
    const int b  = blockIdx.x >> 7;
    const int d  = threadIdx.x & 63;
    const size_t off = (size_t)b * L * D + h * DH + d + (size_t)(c * CH) * D;
    const float* base  = V   + off;
    float*       obase = out + off;
    const float* pb = partial + (size_t)((b * H + h) * 64) * DH + d;
    const int*   fp = flags + (size_t)(b * H + h) * L + c * CH;

    float vals[CH];
    #pragma unroll
    for (int i = 0; i < CH; i++) vals[i] = base[(size_t)i * D];

    float acc = 0.f;
    for (int cc = 0; cc < c; cc++) acc += pb[cc * DH];

    #pragma unroll
    for (int i = 0; i < CH; i++) {
        acc += vals[i];
        obase[(size_t)i * D] = fp[i] ? 0.f : acc;
    }
}

// ---------------------------------------------------------------------------
// Kernel 6: FUSED attention. Grid (keyChunk=16 x 256 keys, bh=16) = 256 blocks.
// Wave w owns keys [j0+64w, j0+64w+64): it computes their exp-scores AND their
// weighted-V contribution -> producer==consumer, ZERO barriers in the u-loop.
// K row per thread in regs (64 VGPR); V[key][d] per lane in vreg[64]; q rows
// in LDS (broadcast). Denominator via wave-reduce + atomicAdd(sums);
// numerator via atomicAdd into the flag-zeroed output row. attn_norm divides.
// ---------------------------------------------------------------------------
__global__ __launch_bounds__(256)
void attn_fused(const float* __restrict__ Q, const float* __restrict__ K,
                const float* __restrict__ V, const int* __restrict__ m_top,
                float* __restrict__ sums, float* __restrict__ out, int NT)
{
    __shared__ float qsh[45][DH];
    __shared__ int   psh[45];
    __shared__ float ssh[256];

    const int bh = blockIdx.y;
    const int h  = bh & (H - 1);
    const int b  = bh >> 3;
    const int j0 = blockIdx.x * 256;
    const int tid = threadIdx.x;
    const int d   = tid & 63;
    const int w   = tid >> 6;

    for (int i = tid; i < NT * DH; i += 256) {
        const int u = i >> 6, dd = i & 63;
        const int p = m_top[bh * NT + u];
        if (dd == 0) psh[u] = p;
        qsh[u][dd] = Q[((size_t)b * L + p) * D + h * DH + dd];
    }

    // K row for this thread's key
    const float* Kb = K + (size_t)b * L * D + h * DH;
    float4 kreg[16];
    {
        const float4* kr = (const float4*)(Kb + (size_t)(j0 + tid) * D);
        #pragma unroll
        for (int i = 0; i < 16; i++) kreg[i] = kr[i];
    }
    // V for this wave's 64 keys, lane = d (coalesced)
    const float* Vb = V + (size_t)b * L * D + h * DH + d;
    const int jb = j0 + w * 64;
    float vreg[64];
    #pragma unroll
    for (int i = 0; i < 64; i++) vreg[i] = Vb[(size_t)(jb + i) * D];
    __syncthreads();                       // qsh/psh ready (only barrier)

    const int j = j0 + tid;
    float* obase = out + (size_t)b * L * D + h * DH;

    for (int u = 0; u < NT; u++) {
        const int p = psh[u];
        if (p < jb) continue;              // wave-uniform skip
        const float4* qv = (const float4*)qsh[u];
        float dot = 0.f;
        #pragma unroll
        for (int i = 0; i < 16; i++) {
            const float4 q4 = qv[i];
            dot += q4.x * kreg[i].x + q4.y * kreg[i].y
                 + q4.z * kreg[i].z + q4.w * kreg[i].w;
        }
        const float e = (j <= p) ? __expf(dot * 0.125f) : 0.f;
        ssh[tid] = e;                      // intra-wave handoff, no barrier
        float t = e;
        #pragma unroll
        for (int off = 32; off; off >>= 1) t += __shfl_xor(t, off, 64);
        if (d == 0) atomicAdd(&sums[bh * NT + u], t);

        const float* wts = &ssh[w * 64];   // own wave's slots (broadcast reads)
        float acc = 0.f;
        #pragma unroll
        for (int i = 0; i < 64; i++) acc += wts[i] * vreg[i];
        atomicAdd(obase + (size_t)p * D + d, acc);
    }
}

// ---------------------------------------------------------------------------
// Kernel 7: divide accumulated numerators by softmax denominators.
// ---------------------------------------------------------------------------
__global__ __launch_bounds__(64)
void attn_norm(const int* __restrict__ m_top, const float* __restrict__ sums,
               float* __restrict__ out, int NT)
{
    const int gu = blockIdx.x;
    const int bh = gu / NT;
    const int h  = bh & (H - 1);
    const int b  = bh >> 3;
    const int p  = m_top[gu];
    float* row = out + ((size_t)b * L + p) * D + h * DH;
    row[threadIdx.x] /= sums[gu];
}

// ---------------------------------------------------------------------------
extern "C" void kernel_launch(void* const* d_in, const int* in_sizes, int n_in,
                              void* d_out, int out_size, void* d_ws, size_t ws_size,
                              hipStream_t stream)
{
    const float* queries = (const float*)d_in[0];
    const float* keys    = (const float*)d_in[1];
    const float* values  = (const float*)d_in[2];
    const float* Wq      = (const float*)d_in[3];
    const float* bq      = (const float*)d_in[4];
    const float* Wk      = (const float*)d_in[5];
    const float* bk      = (const float*)d_in[6];
    const float* Wv      = (const float*)d_in[7];
    const float* bv      = (const float*)d_in[8];
    const int*   idx     = (const int*)d_in[9];
    float* out = (float*)d_out;

    const int S  = in_sizes[9] / L;   // sample_k = 45
    const int NT = S;

    const size_t NE = (size_t)B * L * D;
    float* Qb      = (float*)d_ws;
    float* Kb      = Qb + NE;
    float* Vb      = Kb + NE;
    float* m_buf   = Vb + NE;                           // BH*L
    float* cs_part = m_buf + (size_t)BH * L;            // BH*64*DH
    int*   m_top   = (int*)(cs_part + (size_t)BH * 64 * DH);
    float* sums    = (float*)(m_top + 1024);            // BH*NT
    int*   flags   = (int*)(sums + 1024);               // BH*L
    unsigned short* Xp  = (unsigned short*)(flags + (size_t)BH * L);
    unsigned short* WpT = Xp + (size_t)3 * 8192 * XPW;  // 3*512*K3

    split_x<<<3 * 8192 * 128 / 256, 256, 0, stream>>>(queries, keys, values, Xp);
    split_w<<<dim3(8, 8, 3), 256, 0, stream>>>(Wq, Wk, Wv, WpT);

    gemm_mfma<<<dim3(8192 / 128, 512 / 128, 3), 256, 0, stream>>>(
        Xp, WpT, bq, bk, bv, Qb, Kb, Vb);

    sample_m<<<BH * L / 4, 256, 0, stream>>>(Qb, Kb, idx, m_buf, S);

    topk_kernel<<<BH, 256, 0, stream>>>(m_buf, m_top, sums, flags, NT);

    chunk_sums<<<BH * 16, 256, 0, stream>>>(Vb, cs_part);
    cumsum_write<<<BH * 16, 256, 0, stream>>>(Vb, cs_part, flags, out);

    attn_fused<<<dim3(16, BH), 256, 0, stream>>>(Qb, Kb, Vb, m_top, sums, out, NT);
    attn_norm<<<BH * NT, 64, 0, stream>>>(m_top, sums, out, NT);
}

// Round 11
// 273.466 us; speedup vs baseline: 1.0635x; 1.0635x over previous
//
#include <hip/hip_runtime.h>
#include <math.h>

#define B  2
#define L  4096
#define D  512
#define H  8
#define DH 64
#define BH (B * H)
#define K3 1536          // tripled-K for the bf16 split GEMM (Q,K)
#define XPW 1024         // Xp width: [hi | lo]

typedef short s16x8 __attribute__((ext_vector_type(8)));
typedef float f32x4 __attribute__((ext_vector_type(4)));

#define AS1 __attribute__((address_space(1)))
#define AS3 __attribute__((address_space(3)))

__device__ __forceinline__ void lds_load16(const void* g, void* l) {
    __builtin_amdgcn_global_load_lds((const AS1 unsigned int*)g,
                                     (AS3 unsigned int*)l, 16, 0, 0);
}

__device__ __forceinline__ unsigned short f2bf(float x) {
    union { float f; unsigned u; } v; v.f = x;
    unsigned u = v.u;
    return (unsigned short)((u + 0x7fff + ((u >> 16) & 1)) >> 16);
}
__device__ __forceinline__ float bf2f(unsigned short h) {
    union { float f; unsigned u; } v; v.u = ((unsigned)h) << 16;
    return v.f;
}

// ---------------------------------------------------------------------------
// Fused prep: blocks [0,192) = split_w; [192, 192+12288) = split_x.
// ---------------------------------------------------------------------------
__global__ __launch_bounds__(256)
void k_split(const float* __restrict__ q, const float* __restrict__ k,
             const float* __restrict__ v,
             const float* __restrict__ wq, const float* __restrict__ wk,
             const float* __restrict__ wv,
             unsigned short* __restrict__ Xp, unsigned short* __restrict__ WpT)
{
    const int tid = threadIdx.x;
    if (blockIdx.x < 192) {
        // ---- split_w: W (fp32 [k][n]) -> WpT (bf16 [n][k']): [hi|lo|hi] ----
        __shared__ float t[64][65];
        const int bx = blockIdx.x;
        const int e  = bx >> 6;
        const int k0 = (bx & 7) * 64;
        const int n0 = ((bx >> 3) & 7) * 64;
        const float* W = (e == 0) ? wq : (e == 1) ? wk : wv;

        for (int idx = tid; idx < 64 * 16; idx += 256) {
            const int i = idx >> 4, j4 = (idx & 15) << 2;
            *(float4*)&t[i][j4] = *(const float4*)(W + (size_t)(k0 + i) * 512 + n0 + j4);
        }
        __syncthreads();

        const int n_loc = tid >> 2;
        const int kq    = (tid & 3) << 4;
        unsigned short h[16], l[16];
        #pragma unroll
        for (int tt = 0; tt < 16; tt++) {
            const float x = t[kq + tt][n_loc];
            h[tt] = f2bf(x);
            l[tt] = f2bf(x - bf2f(h[tt]));
        }
        unsigned short* base = WpT + (size_t)e * 512 * K3 + (size_t)(n0 + n_loc) * K3 + k0 + kq;
        #pragma unroll
        for (int g4 = 0; g4 < 4; g4++) {
            ushort4 hv = make_ushort4(h[g4*4], h[g4*4+1], h[g4*4+2], h[g4*4+3]);
            ushort4 lv = make_ushort4(l[g4*4], l[g4*4+1], l[g4*4+2], l[g4*4+3]);
            *(ushort4*)(base + g4*4)        = hv;
            *(ushort4*)(base + 512 + g4*4)  = lv;
            *(ushort4*)(base + 1024 + g4*4) = hv;
        }
    } else {
        // ---- split_x: X (fp32) -> Xp (bf16 [hi|lo]); V stores hi only ----
        const size_t g = (size_t)(blockIdx.x - 192) * 256 + tid;
        const size_t per = (size_t)8192 * 128;
        const int e = (int)(g / per);
        const size_t rem = g - (size_t)e * per;
        const int m  = (int)(rem >> 7);
        const int kq = (int)(rem & 127) << 2;

        const float* X = (e == 0) ? q : (e == 1) ? k : v;
        const float4 x = *(const float4*)(X + (size_t)m * 512 + kq);

        unsigned short h0 = f2bf(x.x), h1 = f2bf(x.y), h2 = f2bf(x.z), h3 = f2bf(x.w);
        unsigned short* dst = Xp + (size_t)e * 8192 * XPW + (size_t)m * XPW + kq;
        *(ushort4*)(dst) = make_ushort4(h0, h1, h2, h3);
        if (e != 2) {
            unsigned short l0 = f2bf(x.x - bf2f(h0)), l1 = f2bf(x.y - bf2f(h1));
            unsigned short l2 = f2bf(x.z - bf2f(h2)), l3 = f2bf(x.w - bf2f(h3));
            *(ushort4*)(dst + 512) = make_ushort4(l0, l1, l2, l3);
        }
    }
}

// ---------------------------------------------------------------------------
// Kernel 1: bf16-split MFMA GEMM. 128x128 tile, BK=32, 4 waves.
// e in {0,1} (Q,K): K'=1536. e==2 (V): K'=512 (hi*hi).
// ---------------------------------------------------------------------------
__global__ __launch_bounds__(256)
void gemm_mfma(const unsigned short* __restrict__ Xp,
               const unsigned short* __restrict__ WpT,
               const float* __restrict__ bq, const float* __restrict__ bk,
               const float* __restrict__ bv,
               float* __restrict__ Qo, float* __restrict__ Ko,
               float* __restrict__ Vo)
{
    __shared__ __align__(16) unsigned short smA[4096];
    __shared__ __align__(16) unsigned short smB[4096];

    const int e = blockIdx.z;
    const float* bias = (e == 0) ? bq : (e == 1) ? bk : bv;
    float* C          = (e == 0) ? Qo : (e == 1) ? Ko : Vo;
    const unsigned short* Ag = Xp  + (size_t)e * 8192 * XPW;
    const unsigned short* Bg = WpT + (size_t)e * 512 * K3;
    const int kEnd = (e == 2) ? 512 : K3;

    const int tid  = threadIdx.x;
    const int lane = tid & 63;
    const int wid  = tid >> 6;
    const int wm   = wid & 1;
    const int wn   = wid >> 1;
    const int m0   = blockIdx.x * 128;
    const int n0g  = blockIdx.y * 128;

    const int r1 = tid >> 2;
    const int c8 = (((tid & 3) ^ ((r1 >> 1) & 3)) << 3);
    const unsigned short* agp = Ag + (size_t)(m0 + r1) * XPW + c8;
    const unsigned short* bgp = Bg + (size_t)(n0g + r1) * K3 + c8;
    unsigned short* lA1 = smA + (size_t)(tid & ~63) * 8;
    unsigned short* lA2 = lA1 + 2048;
    unsigned short* lB1 = smB + (size_t)(tid & ~63) * 8;
    unsigned short* lB2 = lB1 + 2048;

    const int r    = lane & 15;
    const int quad = lane >> 4;
    const int swz  = ((quad ^ ((lane >> 1) & 3)) << 4);
    const char* pA = (const char*)smA + (wm * 64 + r) * 64 + swz;
    const char* pB = (const char*)smB + (wn * 64 + r) * 64 + swz;

    f32x4 acc[4][4];
    #pragma unroll
    for (int i = 0; i < 4; i++)
        #pragma unroll
        for (int j = 0; j < 4; j++)
            acc[i][j] = (f32x4){0.f, 0.f, 0.f, 0.f};

    for (int k0 = 0; k0 < kEnd; k0 += 32) {
        const int kA = (k0 < 512) ? k0 : k0 - 512;
        lds_load16(agp + kA, lA1);
        lds_load16(agp + (size_t)64 * XPW + kA, lA2);
        lds_load16(bgp + k0, lB1);
        lds_load16(bgp + (size_t)64 * K3 + k0, lB2);
        __syncthreads();

        s16x8 af[4], bf[4];
        #pragma unroll
        for (int mt = 0; mt < 4; mt++) af[mt] = *(const s16x8*)(pA + mt * 1024);
        #pragma unroll
        for (int nt = 0; nt < 4; nt++) bf[nt] = *(const s16x8*)(pB + nt * 1024);
        #pragma unroll
        for (int mt = 0; mt < 4; mt++)
            #pragma unroll
            for (int nt = 0; nt < 4; nt++)
                acc[mt][nt] = __builtin_amdgcn_mfma_f32_16x16x32_bf16(
                    af[mt], bf[nt], acc[mt][nt], 0, 0, 0);
        __syncthreads();
    }

    #pragma unroll
    for (int nt = 0; nt < 4; nt++) {
        const int col = n0g + wn * 64 + nt * 16 + r;
        const float bb = bias[col];
        #pragma unroll
        for (int mt = 0; mt < 4; mt++) {
            const int row0 = m0 + wm * 64 + mt * 16 + quad * 4;
            #pragma unroll
            for (int i = 0; i < 4; i++)
                C[(size_t)(row0 + i) * 512 + col] = acc[mt][nt][i] + bb;
        }
    }
}

// ---------------------------------------------------------------------------
// Fused: blocks [0,256) = chunk_sums (bw-bound, launched first);
//        [256, 256+16384) = sample_m (latency-bound, fills behind).
// ---------------------------------------------------------------------------
#define CH 64
__global__ __launch_bounds__(256)
void k_sample_chunks(const float* __restrict__ Q, const float* __restrict__ K,
                     const int* __restrict__ idx, float* __restrict__ m_out, int S,
                     const float* __restrict__ V, float* __restrict__ partial)
{
    const int tid = threadIdx.x;
    if (blockIdx.x < 256) {
        // ---- chunk_sums: per (b,h,chunk,d) partial sums, prefetched ----
        const int bid = blockIdx.x;
        const int c  = (bid & 15) * 4 + (tid >> 6);
        const int h  = (bid >> 4) & (H - 1);
        const int b  = bid >> 7;
        const int d  = tid & 63;
        const float* base = V + (size_t)b * L * D + h * DH + d + (size_t)(c * CH) * D;

        float vals[CH];
        #pragma unroll
        for (int i = 0; i < CH; i++) vals[i] = base[(size_t)i * D];

        float s0 = 0.f, s1 = 0.f, s2 = 0.f, s3 = 0.f;
        #pragma unroll
        for (int i = 0; i < CH; i += 4) {
            s0 += vals[i]; s1 += vals[i+1]; s2 += vals[i+2]; s3 += vals[i+3];
        }
        partial[((size_t)((b * H + h) * 64 + c)) * DH + d] = (s0 + s1) + (s2 + s3);
    } else {
        // ---- sample_m: wave per query, 4-lane cooperative row loads ----
        __shared__ float qs[4][DH];
        const int lane = tid & 63;
        const int wib  = tid >> 6;
        const int wid  = (blockIdx.x - 256) * 4 + wib;
        const int l = wid & (L - 1);
        const int h = (wid >> 12) & (H - 1);
        const int b = wid >> 15;

        qs[wib][lane] = Q[((size_t)b * L + l) * D + h * DH + lane];
        __syncthreads();

        const int r4 = lane >> 2;
        const int c4 = lane & 3;

        float4 qf[4];
        {
            const float4* qv = (const float4*)qs[wib];
            #pragma unroll
            for (int i = 0; i < 4; i++) qf[i] = qv[c4 + 4 * i];
        }

        const float* Kb = K + (size_t)b * L * D + h * DH;
        const int* is = idx + (size_t)l * S;

        float vmax = -INFINITY, vsum = 0.f;
        const int passes = (S + 15) >> 4;
        for (int p = 0; p < passes; p++) {
            const int sp = p * 16 + r4;
            const bool ok = sp < S;
            const int j = ok ? is[sp] : 0;
            const float4* Krow = (const float4*)(Kb + (size_t)j * D);
            float dot = 0.f;
            #pragma unroll
            for (int i = 0; i < 4; i++) {
                const float4 kv = Krow[c4 + 4 * i];
                const float4 qq = qf[i];
                dot += qq.x * kv.x + qq.y * kv.y + qq.z * kv.z + qq.w * kv.w;
            }
            dot += __shfl_xor(dot, 1, 64);
            dot += __shfl_xor(dot, 2, 64);
            if (ok) {
                vmax = fmaxf(vmax, dot);
                if (c4 == 0) vsum += dot;
            }
        }
        #pragma unroll
        for (int off = 32; off; off >>= 1) {
            vmax = fmaxf(vmax, __shfl_xor(vmax, off, 64));
            vsum += __shfl_xor(vsum, off, 64);
        }
        if (lane == 0) m_out[wid] = vmax - vsum * (1.0f / (float)L);
    }
}

// ---------------------------------------------------------------------------
// Kernel 3: exact top-NT via 4-level byte radix-select. One block per (b,h).
// Also zeroes sums[] and writes the selected-row flag array.
// ---------------------------------------------------------------------------
__global__ __launch_bounds__(256)
void topk_kernel(const float* __restrict__ m_in, int* __restrict__ m_top,
                 float* __restrict__ sums, int* __restrict__ flags, int NT)
{
    __shared__ unsigned hist[256];
    __shared__ unsigned sfx[257];
    __shared__ int sh_b, sh_rem;
    __shared__ int cnt_gt, cnt_eq;
    __shared__ int eqlist[128];

    const float* m = m_in + (size_t)blockIdx.x * L;
    const int tid = threadIdx.x;
    int* out = m_top + blockIdx.x * NT;
    int* fl  = flags + (size_t)blockIdx.x * L;

    if (tid < NT) sums[blockIdx.x * NT + tid] = 0.f;
    for (int i = tid; i < L; i += 256) fl[i] = 0;

    unsigned uv[16];
    #pragma unroll
    for (int k = 0; k < 16; k++) {
        const float f = m[tid + k * 256];
        const unsigned x = __float_as_uint(f);
        uv[k] = (x & 0x80000000u) ? ~x : (x | 0x80000000u);
    }

    unsigned prefix = 0;
    int rem = NT;

    for (int level = 0; level < 4; level++) {
        const int shift = 24 - level * 8;
        hist[tid] = 0;
        if (tid == 0) { cnt_gt = 0; cnt_eq = 0; }
        __syncthreads();
        #pragma unroll
        for (int k = 0; k < 16; k++) {
            const bool part = (level == 0) || ((uv[k] >> (shift + 8)) == prefix);
            if (part) atomicAdd(&hist[(uv[k] >> shift) & 255], 1u);
        }
        __syncthreads();
        if (tid < 64) {
            const unsigned s0 = hist[4*tid+0], s1 = hist[4*tid+1];
            const unsigned s2 = hist[4*tid+2], s3 = hist[4*tid+3];
            const unsigned loc = s0 + s1 + s2 + s3;
            unsigned suf = loc;
            #pragma unroll
            for (int off = 1; off < 64; off <<= 1) {
                const unsigned t = __shfl_down(suf, off, 64);
                if (tid + off < 64) suf += t;
            }
            const unsigned tail = suf - loc;
            sfx[4*tid+3] = tail + s3;
            sfx[4*tid+2] = tail + s3 + s2;
            sfx[4*tid+1] = tail + s3 + s2 + s1;
            sfx[4*tid+0] = suf;
            if (tid == 0) sfx[256] = 0;
        }
        __syncthreads();
        if (sfx[tid + 1] < (unsigned)rem && (unsigned)rem <= sfx[tid]) {
            sh_b   = tid;
            sh_rem = rem - (int)sfx[tid + 1];
        }
        __syncthreads();
        prefix = (prefix << 8) | (unsigned)sh_b;
        rem    = sh_rem;
        __syncthreads();
    }

    const unsigned T = prefix;
    const int n_gt = NT - rem;

    #pragma unroll
    for (int k = 0; k < 16; k++) {
        if (uv[k] > T) {
            const int pos = atomicAdd(&cnt_gt, 1);
            out[pos] = tid + k * 256;
        } else if (uv[k] == T) {
            const int pos = atomicAdd(&cnt_eq, 1);
            if (pos < 128) eqlist[pos] = tid + k * 256;
        }
    }
    __syncthreads();
    if (tid == 0) {
        int n = cnt_eq < 128 ? cnt_eq : 128;
        for (int r = 0; r < rem; r++) {
            int best = 0x7fffffff, bi = 0;
            for (int i = 0; i < n; i++)
                if (eqlist[i] < best) { best = eqlist[i]; bi = i; }
            out[n_gt + r] = best;
            eqlist[bi] = 0x7fffffff;
        }
    }
    __syncthreads();
    if (tid < NT) fl[out[tid]] = 1;
}

// ---------------------------------------------------------------------------
// Fused: blocks [0,256) = cumsum_write (flag-gated zero of selected rows);
//        [256, 256+384) = attn_scores (exp-scores + per-u sums).
// Both depend only on topk/chunk_sums outputs; no intra-launch conflicts
// (cumsum writes out; scores writes scores/sums).
// ---------------------------------------------------------------------------
__global__ __launch_bounds__(256)
void k_cumsum_scores(const float* __restrict__ V, const float* __restrict__ partial,
                     const int* __restrict__ flags, float* __restrict__ out,
                     const float* __restrict__ Q, const float* __restrict__ K,
                     const int* __restrict__ m_top, float* __restrict__ scores,
                     float* __restrict__ sums, int NT)
{
    const int tid = threadIdx.x;
    if (blockIdx.x < 256) {
        // ---- cumsum_write ----
        const int bid = blockIdx.x;
        const int c  = (bid & 15) * 4 + (tid >> 6);
        const int h  = (bid >> 4) & (H - 1);
        const int b  = bid >> 7;
        const int d  = tid & 63;
        const size_t off = (size_t)b * L * D + h * DH + d + (size_t)(c * CH) * D;
        const float* base  = V   + off;
        float*       obase = out + off;
        const float* pb = partial + (size_t)((b * H + h) * 64) * DH + d;
        const int*   fp = flags + (size_t)(b * H + h) * L + c * CH;

        float vals[CH];
        #pragma unroll
        for (int i = 0; i < CH; i++) vals[i] = base[(size_t)i * D];

        float acc = 0.f;
        for (int cc = 0; cc < c; cc++) acc += pb[cc * DH];

        #pragma unroll
        for (int i = 0; i < CH; i++) {
            acc += vals[i];
            obase[(size_t)i * D] = fp[i] ? 0.f : acc;
        }
    } else {
        // ---- attn_scores: 384 blocks = (jc=8, ug=3, bh=16) ----
        __shared__ float qsh[15][DH];
        __shared__ int   psh[15];

        const int rem2 = blockIdx.x - 256;
        const int bh = rem2 / 24;
        const int r2 = rem2 % 24;
        const int ug = r2 >> 3;
        const int jc = r2 & 7;
        const int h  = bh & (H - 1);
        const int b  = bh >> 3;
        const int j0 = jc * 512;

        for (int i = tid; i < 15 * DH; i += 256) {
            const int u = i >> 6, d = i & 63;
            const int p = m_top[bh * NT + ug * 15 + u];
            if (d == 0) psh[u] = p;
            qsh[u][d] = Q[((size_t)b * L + p) * D + h * DH + d];
        }
        __syncthreads();

        const float* Kb = K + (size_t)b * L * D + h * DH;
        const int ja = j0 + tid;
        const int jb = ja + 256;
        float4 k0[16], k1[16];
        {
            const float4* ra = (const float4*)(Kb + (size_t)ja * D);
            const float4* rb = (const float4*)(Kb + (size_t)jb * D);
            #pragma unroll
            for (int i = 0; i < 16; i++) { k0[i] = ra[i]; k1[i] = rb[i]; }
        }

        for (int u = 0; u < 15; u++) {
            const int p = psh[u];
            const float4* qv = (const float4*)qsh[u];
            float d0 = 0.f, d1 = 0.f;
            #pragma unroll
            for (int i = 0; i < 16; i++) {
                const float4 q4 = qv[i];
                d0 += q4.x * k0[i].x + q4.y * k0[i].y + q4.z * k0[i].z + q4.w * k0[i].w;
                d1 += q4.x * k1[i].x + q4.y * k1[i].y + q4.z * k1[i].z + q4.w * k1[i].w;
            }
            const float e0 = (ja <= p) ? __expf(d0 * 0.125f) : 0.f;
            const float e1 = (jb <= p) ? __expf(d1 * 0.125f) : 0.f;
            float* srow = scores + (size_t)(bh * NT + ug * 15 + u) * L;
            srow[ja] = e0;
            srow[jb] = e1;
            float t = e0 + e1;
            #pragma unroll
            for (int off = 32; off; off >>= 1) t += __shfl_xor(t, off, 64);
            if ((tid & 63) == 0) atomicAdd(&sums[bh * NT + ug * 15 + u], t);
        }
    }
}

// ---------------------------------------------------------------------------
// Kernel 6c: weighted-V accumulate into flag-zeroed output rows via atomics.
// Grid (keyChunk=64, bh=16) = 1024 blocks.
// ---------------------------------------------------------------------------
__global__ __launch_bounds__(256)
void attn_wv(const float* __restrict__ scores, const float* __restrict__ V,
             const int* __restrict__ m_top, const float* __restrict__ sums,
             float* __restrict__ out, int NT)
{
    __shared__ float ssh[45][64];
    __shared__ float sinv[45];
    __shared__ int   psh[45];

    const int bh = blockIdx.y;
    const int h  = bh & (H - 1);
    const int b  = bh >> 3;
    const int j0 = blockIdx.x * 64;
    const int tid = threadIdx.x;
    const int d   = tid & 63;
    const int w   = tid >> 6;

    if (tid < NT) {
        psh[tid]  = m_top[bh * NT + tid];
        sinv[tid] = 1.0f / sums[bh * NT + tid];
    }

    const float* Vb = V + (size_t)b * L * D + h * DH + d;
    float vreg[64];
    #pragma unroll
    for (int i = 0; i < 64; i++) vreg[i] = Vb[(size_t)(j0 + i) * D];

    __syncthreads();
    for (int i = tid; i < NT * 64; i += 256) {
        const int u = i >> 6, j = i & 63;
        ssh[u][j] = scores[(size_t)(bh * NT + u) * L + j0 + j] * sinv[u];
    }
    __syncthreads();

    for (int u = w; u < NT; u += 4) {
        const int p = psh[u];
        if (p < j0) continue;
        const float* wt = ssh[u];
        float acc = 0.f;
        #pragma unroll
        for (int i = 0; i < 64; i++) acc += wt[i] * vreg[i];
        atomicAdd(out + ((size_t)b * L + p) * D + h * DH + d, acc);
    }
}

// ---------------------------------------------------------------------------
extern "C" void kernel_launch(void* const* d_in, const int* in_sizes, int n_in,
                              void* d_out, int out_size, void* d_ws, size_t ws_size,
                              hipStream_t stream)
{
    const float* queries = (const float*)d_in[0];
    const float* keys    = (const float*)d_in[1];
    const float* values  = (const float*)d_in[2];
    const float* Wq      = (const float*)d_in[3];
    const float* bq      = (const float*)d_in[4];
    const float* Wk      = (const float*)d_in[5];
    const float* bk      = (const float*)d_in[6];
    const float* Wv      = (const float*)d_in[7];
    const float* bv      = (const float*)d_in[8];
    const int*   idx     = (const int*)d_in[9];
    float* out = (float*)d_out;

    const int S  = in_sizes[9] / L;   // sample_k = 45
    const int NT = S;

    const size_t NE = (size_t)B * L * D;
    float* Qb      = (float*)d_ws;
    float* Kb      = Qb + NE;
    float* Vb      = Kb + NE;
    float* m_buf   = Vb + NE;                           // BH*L
    float* cs_part = m_buf + (size_t)BH * L;            // BH*64*DH
    int*   m_top   = (int*)(cs_part + (size_t)BH * 64 * DH);
    float* sums    = (float*)(m_top + 1024);            // BH*NT
    int*   flags   = (int*)(sums + 1024);               // BH*L
    float* scores  = (float*)(flags + (size_t)BH * L);  // BH*NT*L
    unsigned short* Xp  = (unsigned short*)(scores + (size_t)BH * NT * L);
    unsigned short* WpT = Xp + (size_t)3 * 8192 * XPW;  // 3*512*K3

    k_split<<<192 + 3 * 8192 * 128 / 256, 256, 0, stream>>>(
        queries, keys, values, Wq, Wk, Wv, Xp, WpT);

    gemm_mfma<<<dim3(8192 / 128, 512 / 128, 3), 256, 0, stream>>>(
        Xp, WpT, bq, bk, bv, Qb, Kb, Vb);

    k_sample_chunks<<<256 + BH * L / 4, 256, 0, stream>>>(
        Qb, Kb, idx, m_buf, S, Vb, cs_part);

    topk_kernel<<<BH, 256, 0, stream>>>(m_buf, m_top, sums, flags, NT);

    k_cumsum_scores<<<256 + 384, 256, 0, stream>>>(
        Vb, cs_part, flags, out, Qb, Kb, m_top, scores, sums, NT);

    attn_wv<<<dim3(64, BH), 256, 0, stream>>>(scores, Vb, m_top, sums, out, NT);
}

// Round 12
// 270.382 us; speedup vs baseline: 1.0757x; 1.0114x over previous
//
#include <hip/hip_runtime.h>
#include <math.h>

#define B  2
#define L  4096
#define D  512
#define H  8
#define DH 64
#define BH (B * H)
#define K3 1536          // tripled-K for the bf16 split GEMM (Q,K)
#define XPW 1024         // Xp width: [hi | lo]

typedef short s16x8 __attribute__((ext_vector_type(8)));
typedef float f32x4 __attribute__((ext_vector_type(4)));

#define AS1 __attribute__((address_space(1)))
#define AS3 __attribute__((address_space(3)))

__device__ __forceinline__ void lds_load16(const void* g, void* l) {
    __builtin_amdgcn_global_load_lds((const AS1 unsigned int*)g,
                                     (AS3 unsigned int*)l, 16, 0, 0);
}

__device__ __forceinline__ unsigned short f2bf(float x) {
    union { float f; unsigned u; } v; v.f = x;
    unsigned u = v.u;
    return (unsigned short)((u + 0x7fff + ((u >> 16) & 1)) >> 16);
}
__device__ __forceinline__ float bf2f(unsigned short h) {
    union { float f; unsigned u; } v; v.u = ((unsigned)h) << 16;
    return v.f;
}

// ---------------------------------------------------------------------------
// Fused prep: blocks [0,192) = split_w; [192, 192+12288) = split_x.
// ---------------------------------------------------------------------------
__global__ __launch_bounds__(256)
void k_split(const float* __restrict__ q, const float* __restrict__ k,
             const float* __restrict__ v,
             const float* __restrict__ wq, const float* __restrict__ wk,
             const float* __restrict__ wv,
             unsigned short* __restrict__ Xp, unsigned short* __restrict__ WpT)
{
    const int tid = threadIdx.x;
    if (blockIdx.x < 192) {
        __shared__ float t[64][65];
        const int bx = blockIdx.x;
        const int e  = bx >> 6;
        const int k0 = (bx & 7) * 64;
        const int n0 = ((bx >> 3) & 7) * 64;
        const float* W = (e == 0) ? wq : (e == 1) ? wk : wv;

        for (int idx = tid; idx < 64 * 16; idx += 256) {
            const int i = idx >> 4, j4 = (idx & 15) << 2;
            *(float4*)&t[i][j4] = *(const float4*)(W + (size_t)(k0 + i) * 512 + n0 + j4);
        }
        __syncthreads();

        const int n_loc = tid >> 2;
        const int kq    = (tid & 3) << 4;
        unsigned short h[16], l[16];
        #pragma unroll
        for (int tt = 0; tt < 16; tt++) {
            const float x = t[kq + tt][n_loc];
            h[tt] = f2bf(x);
            l[tt] = f2bf(x - bf2f(h[tt]));
        }
        unsigned short* base = WpT + (size_t)e * 512 * K3 + (size_t)(n0 + n_loc) * K3 + k0 + kq;
        #pragma unroll
        for (int g4 = 0; g4 < 4; g4++) {
            ushort4 hv = make_ushort4(h[g4*4], h[g4*4+1], h[g4*4+2], h[g4*4+3]);
            ushort4 lv = make_ushort4(l[g4*4], l[g4*4+1], l[g4*4+2], l[g4*4+3]);
            *(ushort4*)(base + g4*4)        = hv;
            *(ushort4*)(base + 512 + g4*4)  = lv;
            *(ushort4*)(base + 1024 + g4*4) = hv;
        }
    } else {
        const size_t g = (size_t)(blockIdx.x - 192) * 256 + tid;
        const size_t per = (size_t)8192 * 128;
        const int e = (int)(g / per);
        const size_t rem = g - (size_t)e * per;
        const int m  = (int)(rem >> 7);
        const int kq = (int)(rem & 127) << 2;

        const float* X = (e == 0) ? q : (e == 1) ? k : v;
        const float4 x = *(const float4*)(X + (size_t)m * 512 + kq);

        unsigned short h0 = f2bf(x.x), h1 = f2bf(x.y), h2 = f2bf(x.z), h3 = f2bf(x.w);
        unsigned short* dst = Xp + (size_t)e * 8192 * XPW + (size_t)m * XPW + kq;
        *(ushort4*)(dst) = make_ushort4(h0, h1, h2, h3);
        if (e != 2) {
            unsigned short l0 = f2bf(x.x - bf2f(h0)), l1 = f2bf(x.y - bf2f(h1));
            unsigned short l2 = f2bf(x.z - bf2f(h2)), l3 = f2bf(x.w - bf2f(h3));
            *(ushort4*)(dst + 512) = make_ushort4(l0, l1, l2, l3);
        }
    }
}

// ---------------------------------------------------------------------------
// Kernel 1: bf16-split MFMA GEMM. 128x128 tile, BK=32, 4 waves.
// ---------------------------------------------------------------------------
__global__ __launch_bounds__(256)
void gemm_mfma(const unsigned short* __restrict__ Xp,
               const unsigned short* __restrict__ WpT,
               const float* __restrict__ bq, const float* __restrict__ bk,
               const float* __restrict__ bv,
               float* __restrict__ Qo, float* __restrict__ Ko,
               float* __restrict__ Vo)
{
    __shared__ __align__(16) unsigned short smA[4096];
    __shared__ __align__(16) unsigned short smB[4096];

    const int e = blockIdx.z;
    const float* bias = (e == 0) ? bq : (e == 1) ? bk : bv;
    float* C          = (e == 0) ? Qo : (e == 1) ? Ko : Vo;
    const unsigned short* Ag = Xp  + (size_t)e * 8192 * XPW;
    const unsigned short* Bg = WpT + (size_t)e * 512 * K3;
    const int kEnd = (e == 2) ? 512 : K3;

    const int tid  = threadIdx.x;
    const int lane = tid & 63;
    const int wid  = tid >> 6;
    const int wm   = wid & 1;
    const int wn   = wid >> 1;
    const int m0   = blockIdx.x * 128;
    const int n0g  = blockIdx.y * 128;

    const int r1 = tid >> 2;
    const int c8 = (((tid & 3) ^ ((r1 >> 1) & 3)) << 3);
    const unsigned short* agp = Ag + (size_t)(m0 + r1) * XPW + c8;
    const unsigned short* bgp = Bg + (size_t)(n0g + r1) * K3 + c8;
    unsigned short* lA1 = smA + (size_t)(tid & ~63) * 8;
    unsigned short* lA2 = lA1 + 2048;
    unsigned short* lB1 = smB + (size_t)(tid & ~63) * 8;
    unsigned short* lB2 = lB1 + 2048;

    const int r    = lane & 15;
    const int quad = lane >> 4;
    const int swz  = ((quad ^ ((lane >> 1) & 3)) << 4);
    const char* pA = (const char*)smA + (wm * 64 + r) * 64 + swz;
    const char* pB = (const char*)smB + (wn * 64 + r) * 64 + swz;

    f32x4 acc[4][4];
    #pragma unroll
    for (int i = 0; i < 4; i++)
        #pragma unroll
        for (int j = 0; j < 4; j++)
            acc[i][j] = (f32x4){0.f, 0.f, 0.f, 0.f};

    for (int k0 = 0; k0 < kEnd; k0 += 32) {
        const int kA = (k0 < 512) ? k0 : k0 - 512;
        lds_load16(agp + kA, lA1);
        lds_load16(agp + (size_t)64 * XPW + kA, lA2);
        lds_load16(bgp + k0, lB1);
        lds_load16(bgp + (size_t)64 * K3 + k0, lB2);
        __syncthreads();

        s16x8 af[4], bf[4];
        #pragma unroll
        for (int mt = 0; mt < 4; mt++) af[mt] = *(const s16x8*)(pA + mt * 1024);
        #pragma unroll
        for (int nt = 0; nt < 4; nt++) bf[nt] = *(const s16x8*)(pB + nt * 1024);
        #pragma unroll
        for (int mt = 0; mt < 4; mt++)
            #pragma unroll
            for (int nt = 0; nt < 4; nt++)
                acc[mt][nt] = __builtin_amdgcn_mfma_f32_16x16x32_bf16(
                    af[mt], bf[nt], acc[mt][nt], 0, 0, 0);
        __syncthreads();
    }

    #pragma unroll
    for (int nt = 0; nt < 4; nt++) {
        const int col = n0g + wn * 64 + nt * 16 + r;
        const float bb = bias[col];
        #pragma unroll
        for (int mt = 0; mt < 4; mt++) {
            const int row0 = m0 + wm * 64 + mt * 16 + quad * 4;
            #pragma unroll
            for (int i = 0; i < 4; i++)
                C[(size_t)(row0 + i) * 512 + col] = acc[mt][nt][i] + bb;
        }
    }
}

// ---------------------------------------------------------------------------
// Fused: blocks [0,256) = chunk_sums; [256, 256+16384) = sample_m.
// sample_m blocks are XCD-SWIZZLED: flat index i -> bh = i & 15, so all
// blocks of one (b,h) land on XCD bh%8 (round-robin dispatch) and that
// bh's 1 MB K strip stays in ONE per-XCD L2 instead of being duplicated
// into all 8 (was 82 MB HBM FETCH vs 51 MB unique).
// ---------------------------------------------------------------------------
#define CH 64
__global__ __launch_bounds__(256)
void k_sample_chunks(const float* __restrict__ Q, const float* __restrict__ K,
                     const int* __restrict__ idx, float* __restrict__ m_out, int S,
                     const float* __restrict__ V, float* __restrict__ partial)
{
    const int tid = threadIdx.x;
    if (blockIdx.x < 256) {
        const int bid = blockIdx.x;
        const int c  = (bid & 15) * 4 + (tid >> 6);
        const int h  = (bid >> 4) & (H - 1);
        const int b  = bid >> 7;
        const int d  = tid & 63;
        const float* base = V + (size_t)b * L * D + h * DH + d + (size_t)(c * CH) * D;

        float vals[CH];
        #pragma unroll
        for (int i = 0; i < CH; i++) vals[i] = base[(size_t)i * D];

        float s0 = 0.f, s1 = 0.f, s2 = 0.f, s3 = 0.f;
        #pragma unroll
        for (int i = 0; i < CH; i += 4) {
            s0 += vals[i]; s1 += vals[i+1]; s2 += vals[i+2]; s3 += vals[i+3];
        }
        partial[((size_t)((b * H + h) * 64 + c)) * DH + d] = (s0 + s1) + (s2 + s3);
    } else {
        __shared__ float qs[4][DH];
        const int lane = tid & 63;
        const int wib  = tid >> 6;
        const int i    = blockIdx.x - 256;          // 0..16383
        const int bh   = i & 15;                    // XCD swizzle: bh fastest
        const int lg   = i >> 4;                    // l-group 0..1023
        const int l = lg * 4 + wib;
        const int h = bh & (H - 1);
        const int b = bh >> 3;
        const int wid = (bh << 12) | l;             // m_out index (b,h,l flat)

        qs[wib][lane] = Q[((size_t)b * L + l) * D + h * DH + lane];
        __syncthreads();

        const int r4 = lane >> 2;
        const int c4 = lane & 3;

        float4 qf[4];
        {
            const float4* qv = (const float4*)qs[wib];
            #pragma unroll
            for (int ii = 0; ii < 4; ii++) qf[ii] = qv[c4 + 4 * ii];
        }

        const float* Kb = K + (size_t)b * L * D + h * DH;
        const int* is = idx + (size_t)l * S;

        float vmax = -INFINITY, vsum = 0.f;
        const int passes = (S + 15) >> 4;
        for (int p = 0; p < passes; p++) {
            const int sp = p * 16 + r4;
            const bool ok = sp < S;
            const int j = ok ? is[sp] : 0;
            const float4* Krow = (const float4*)(Kb + (size_t)j * D);
            float dot = 0.f;
            #pragma unroll
            for (int ii = 0; ii < 4; ii++) {
                const float4 kv = Krow[c4 + 4 * ii];
                const float4 qq = qf[ii];
                dot += qq.x * kv.x + qq.y * kv.y + qq.z * kv.z + qq.w * kv.w;
            }
            dot += __shfl_xor(dot, 1, 64);
            dot += __shfl_xor(dot, 2, 64);
            if (ok) {
                vmax = fmaxf(vmax, dot);
                if (c4 == 0) vsum += dot;
            }
        }
        #pragma unroll
        for (int off = 32; off; off >>= 1) {
            vmax = fmaxf(vmax, __shfl_xor(vmax, off, 64));
            vsum += __shfl_xor(vsum, off, 64);
        }
        if (lane == 0) m_out[wid] = vmax - vsum * (1.0f / (float)L);
    }
}

// ---------------------------------------------------------------------------
// Kernel 3: exact top-NT via 4-level byte radix-select. One block per (b,h).
// Also zeroes sums[] and writes the selected-row flag array.
// ---------------------------------------------------------------------------
__global__ __launch_bounds__(256)
void topk_kernel(const float* __restrict__ m_in, int* __restrict__ m_top,
                 float* __restrict__ sums, int* __restrict__ flags, int NT)
{
    __shared__ unsigned hist[256];
    __shared__ unsigned sfx[257];
    __shared__ int sh_b, sh_rem;
    __shared__ int cnt_gt, cnt_eq;
    __shared__ int eqlist[128];

    const float* m = m_in + (size_t)blockIdx.x * L;
    const int tid = threadIdx.x;
    int* out = m_top + blockIdx.x * NT;
    int* fl  = flags + (size_t)blockIdx.x * L;

    if (tid < NT) sums[blockIdx.x * NT + tid] = 0.f;
    for (int i = tid; i < L; i += 256) fl[i] = 0;

    unsigned uv[16];
    #pragma unroll
    for (int k = 0; k < 16; k++) {
        const float f = m[tid + k * 256];
        const unsigned x = __float_as_uint(f);
        uv[k] = (x & 0x80000000u) ? ~x : (x | 0x80000000u);
    }

    unsigned prefix = 0;
    int rem = NT;

    for (int level = 0; level < 4; level++) {
        const int shift = 24 - level * 8;
        hist[tid] = 0;
        if (tid == 0) { cnt_gt = 0; cnt_eq = 0; }
        __syncthreads();
        #pragma unroll
        for (int k = 0; k < 16; k++) {
            const bool part = (level == 0) || ((uv[k] >> (shift + 8)) == prefix);
            if (part) atomicAdd(&hist[(uv[k] >> shift) & 255], 1u);
        }
        __syncthreads();
        if (tid < 64) {
            const unsigned s0 = hist[4*tid+0], s1 = hist[4*tid+1];
            const unsigned s2 = hist[4*tid+2], s3 = hist[4*tid+3];
            const unsigned loc = s0 + s1 + s2 + s3;
            unsigned suf = loc;
            #pragma unroll
            for (int off = 1; off < 64; off <<= 1) {
                const unsigned t = __shfl_down(suf, off, 64);
                if (tid + off < 64) suf += t;
            }
            const unsigned tail = suf - loc;
            sfx[4*tid+3] = tail + s3;
            sfx[4*tid+2] = tail + s3 + s2;
            sfx[4*tid+1] = tail + s3 + s2 + s1;
            sfx[4*tid+0] = suf;
            if (tid == 0) sfx[256] = 0;
        }
        __syncthreads();
        if (sfx[tid + 1] < (unsigned)rem && (unsigned)rem <= sfx[tid]) {
            sh_b   = tid;
            sh_rem = rem - (int)sfx[tid + 1];
        }
        __syncthreads();
        prefix = (prefix << 8) | (unsigned)sh_b;
        rem    = sh_rem;
        __syncthreads();
    }

    const unsigned T = prefix;
    const int n_gt = NT - rem;

    #pragma unroll
    for (int k = 0; k < 16; k++) {
        if (uv[k] > T) {
            const int pos = atomicAdd(&cnt_gt, 1);
            out[pos] = tid + k * 256;
        } else if (uv[k] == T) {
            const int pos = atomicAdd(&cnt_eq, 1);
            if (pos < 128) eqlist[pos] = tid + k * 256;
        }
    }
    __syncthreads();
    if (tid == 0) {
        int n = cnt_eq < 128 ? cnt_eq : 128;
        for (int r = 0; r < rem; r++) {
            int best = 0x7fffffff, bi = 0;
            for (int i = 0; i < n; i++)
                if (eqlist[i] < best) { best = eqlist[i]; bi = i; }
            out[n_gt + r] = best;
            eqlist[bi] = 0x7fffffff;
        }
    }
    __syncthreads();
    if (tid < NT) fl[out[tid]] = 1;
}

// ---------------------------------------------------------------------------
// Fused: blocks [0,256) = cumsum_write; [256, 256+384) = attn_scores.
// ---------------------------------------------------------------------------
__global__ __launch_bounds__(256)
void k_cumsum_scores(const float* __restrict__ V, const float* __restrict__ partial,
                     const int* __restrict__ flags, float* __restrict__ out,
                     const float* __restrict__ Q, const float* __restrict__ K,
                     const int* __restrict__ m_top, float* __restrict__ scores,
                     float* __restrict__ sums, int NT)
{
    const int tid = threadIdx.x;
    if (blockIdx.x < 256) {
        const int bid = blockIdx.x;
        const int c  = (bid & 15) * 4 + (tid >> 6);
        const int h  = (bid >> 4) & (H - 1);
        const int b  = bid >> 7;
        const int d  = tid & 63;
        const size_t off = (size_t)b * L * D + h * DH + d + (size_t)(c * CH) * D;
        const float* base  = V   + off;
        float*       obase = out + off;
        const float* pb = partial + (size_t)((b * H + h) * 64) * DH + d;
        const int*   fp = flags + (size_t)(b * H + h) * L + c * CH;

        float vals[CH];
        #pragma unroll
        for (int i = 0; i < CH; i++) vals[i] = base[(size_t)i * D];

        float acc = 0.f;
        for (int cc = 0; cc < c; cc++) acc += pb[cc * DH];

        #pragma unroll
        for (int i = 0; i < CH; i++) {
            acc += vals[i];
            obase[(size_t)i * D] = fp[i] ? 0.f : acc;
        }
    } else {
        __shared__ float qsh[15][DH];
        __shared__ int   psh[15];

        const int rem2 = blockIdx.x - 256;
        const int bh = rem2 / 24;
        const int r2 = rem2 % 24;
        const int ug = r2 >> 3;
        const int jc = r2 & 7;
        const int h  = bh & (H - 1);
        const int b  = bh >> 3;
        const int j0 = jc * 512;

        for (int i = tid; i < 15 * DH; i += 256) {
            const int u = i >> 6, d = i & 63;
            const int p = m_top[bh * NT + ug * 15 + u];
            if (d == 0) psh[u] = p;
            qsh[u][d] = Q[((size_t)b * L + p) * D + h * DH + d];
        }
        __syncthreads();

        const float* Kb = K + (size_t)b * L * D + h * DH;
        const int ja = j0 + tid;
        const int jb = ja + 256;
        float4 k0[16], k1[16];
        {
            const float4* ra = (const float4*)(Kb + (size_t)ja * D);
            const float4* rb = (const float4*)(Kb + (size_t)jb * D);
            #pragma unroll
            for (int i = 0; i < 16; i++) { k0[i] = ra[i]; k1[i] = rb[i]; }
        }

        for (int u = 0; u < 15; u++) {
            const int p = psh[u];
            const float4* qv = (const float4*)qsh[u];
            float d0 = 0.f, d1 = 0.f;
            #pragma unroll
            for (int i = 0; i < 16; i++) {
                const float4 q4 = qv[i];
                d0 += q4.x * k0[i].x + q4.y * k0[i].y + q4.z * k0[i].z + q4.w * k0[i].w;
                d1 += q4.x * k1[i].x + q4.y * k1[i].y + q4.z * k1[i].z + q4.w * k1[i].w;
            }
            const float e0 = (ja <= p) ? __expf(d0 * 0.125f) : 0.f;
            const float e1 = (jb <= p) ? __expf(d1 * 0.125f) : 0.f;
            float* srow = scores + (size_t)(bh * NT + ug * 15 + u) * L;
            srow[ja] = e0;
            srow[jb] = e1;
            float t = e0 + e1;
            #pragma unroll
            for (int off = 32; off; off >>= 1) t += __shfl_xor(t, off, 64);
            if ((tid & 63) == 0) atomicAdd(&sums[bh * NT + ug * 15 + u], t);
        }
    }
}

// ---------------------------------------------------------------------------
// Kernel 6c: weighted-V accumulate into flag-zeroed output rows via atomics.
// ---------------------------------------------------------------------------
__global__ __launch_bounds__(256)
void attn_wv(const float* __restrict__ scores, const float* __restrict__ V,
             const int* __restrict__ m_top, const float* __restrict__ sums,
             float* __restrict__ out, int NT)
{
    __shared__ float ssh[45][64];
    __shared__ float sinv[45];
    __shared__ int   psh[45];

    const int bh = blockIdx.y;
    const int h  = bh & (H - 1);
    const int b  = bh >> 3;
    const int j0 = blockIdx.x * 64;
    const int tid = threadIdx.x;
    const int d   = tid & 63;
    const int w   = tid >> 6;

    if (tid < NT) {
        psh[tid]  = m_top[bh * NT + tid];
        sinv[tid] = 1.0f / sums[bh * NT + tid];
    }

    const float* Vb = V + (size_t)b * L * D + h * DH + d;
    float vreg[64];
    #pragma unroll
    for (int i = 0; i < 64; i++) vreg[i] = Vb[(size_t)(j0 + i) * D];

    __syncthreads();
    for (int i = tid; i < NT * 64; i += 256) {
        const int u = i >> 6, j = i & 63;
        ssh[u][j] = scores[(size_t)(bh * NT + u) * L + j0 + j] * sinv[u];
    }
    __syncthreads();

    for (int u = w; u < NT; u += 4) {
        const int p = psh[u];
        if (p < j0) continue;
        const float* wt = ssh[u];
        float acc = 0.f;
        #pragma unroll
        for (int i = 0; i < 64; i++) acc += wt[i] * vreg[i];
        atomicAdd(out + ((size_t)b * L + p) * D + h * DH + d, acc);
    }
}

// ---------------------------------------------------------------------------
extern "C" void kernel_launch(void* const* d_in, const int* in_sizes, int n_in,
                              void* d_out, int out_size, void* d_ws, size_t ws_size,
                              hipStream_t stream)
{
    const float* queries = (const float*)d_in[0];
    const float* keys    = (const float*)d_in[1];
    const float* values  = (const float*)d_in[2];
    const float* Wq      = (const float*)d_in[3];
    const float* bq      = (const float*)d_in[4];
    const float* Wk      = (const float*)d_in[5];
    const float* bk      = (const float*)d_in[6];
    const float* Wv      = (const float*)d_in[7];
    const float* bv      = (const float*)d_in[8];
    const int*   idx     = (const int*)d_in[9];
    float* out = (float*)d_out;

    const int S  = in_sizes[9] / L;   // sample_k = 45
    const int NT = S;

    const size_t NE = (size_t)B * L * D;
    float* Qb      = (float*)d_ws;
    float* Kb      = Qb + NE;
    float* Vb      = Kb + NE;
    float* m_buf   = Vb + NE;                           // BH*L
    float* cs_part = m_buf + (size_t)BH * L;            // BH*64*DH
    int*   m_top   = (int*)(cs_part + (size_t)BH * 64 * DH);
    float* sums    = (float*)(m_top + 1024);            // BH*NT
    int*   flags   = (int*)(sums + 1024);               // BH*L
    float* scores  = (float*)(flags + (size_t)BH * L);  // BH*NT*L
    unsigned short* Xp  = (unsigned short*)(scores + (size_t)BH * NT * L);
    unsigned short* WpT = Xp + (size_t)3 * 8192 * XPW;  // 3*512*K3

    k_split<<<192 + 3 * 8192 * 128 / 256, 256, 0, stream>>>(
        queries, keys, values, Wq, Wk, Wv, Xp, WpT);

    gemm_mfma<<<dim3(8192 / 128, 512 / 128, 3), 256, 0, stream>>>(
        Xp, WpT, bq, bk, bv, Qb, Kb, Vb);

    k_sample_chunks<<<256 + BH * L / 4, 256, 0, stream>>>(
        Qb, Kb, idx, m_buf, S, Vb, cs_part);

    topk_kernel<<<BH, 256, 0, stream>>>(m_buf, m_top, sums, flags, NT);

    k_cumsum_scores<<<256 + 384, 256, 0, stream>>>(
        Vb, cs_part, flags, out, Qb, Kb, m_top, scores, sums, NT);

    attn_wv<<<dim3(64, BH), 256, 0, stream>>>(scores, Vb, m_top, sums, out, NT);
}